// Round 1
// baseline (478.564 us; speedup 1.0000x reference)
//
#include <hip/hip_runtime.h>
#include <hip/hip_bf16.h>
#include <math.h>

#define N_NODES 100000
#define N_EDGES 1600000
#define D 128
#define NEG 0.2f
#define LN_EPS 1e-5f

#define GEMM_BLOCKS ((N_NODES + 63) / 64)     // 1563 (64 rows/block)
#define PLACE_BLOCKS ((N_EDGES + 2047) / 2048) // 782 (2048 edges/block, 8/thread)

typedef __attribute__((ext_vector_type(8))) short bf16x8;
typedef __attribute__((ext_vector_type(4))) float f32x4;

__device__ __forceinline__ float lrelu(float v){ return fmaxf(v, NEG * v); }
__device__ __forceinline__ float gelu_exact(float v){ return 0.5f * v * (1.0f + erff(v * 0.7071067811865476f)); }
__device__ __forceinline__ float wave_sum(float v){
#pragma unroll
  for (int o = 32; o; o >>= 1) v += __shfl_xor(v, o, 64);
  return v;
}
__device__ __forceinline__ unsigned short f2bf(float f){
  __hip_bfloat16 h = __float2bfloat16(f);            // RNE
  return *(unsigned short*)&h;
}
// bf16 pair unpack: low 16 bits = even col, high = odd col
__device__ __forceinline__ float bf_lo(unsigned u){ return __uint_as_float(u << 16); }
__device__ __forceinline__ float bf_hi(unsigned u){ return __uint_as_float(u & 0xFFFF0000u); }

// ---------------- prep: W -> B-fragment bf16 layout + c_e ----------------
// Wfrag slot = ((l*8+ct)*4+kc)*64+lane, 8 bf16 each:
//   Wfrag[slot][j] = bf16( W[l][ kc*32 + (lane>>4)*8 + j ][ ct*16 + (lane&15) ] )
__global__ __launch_bounds__(256) void k_prep(const float* __restrict__ W,
                                              unsigned short* __restrict__ wfrag,
                                              const float* __restrict__ lew,
                                              const float* __restrict__ ae,
                                              float* __restrict__ c_e){
  if (threadIdx.x < 128){
    int l = threadIdx.x >> 6;
    int lane = threadIdx.x & 63;
    const float* a = lew + l * D;
    const float* b = ae + l * D;
    float v = a[lane] * b[lane] + a[64 + lane] * b[64 + lane];
    v = wave_sum(v);
    if (lane == 0) c_e[l] = v;
  }
#pragma unroll
  for (int it = 0; it < 16; it++){
    int slot = it * 256 + threadIdx.x;               // 4096 slots
    int lane = slot & 63;
    int kc   = (slot >> 6) & 3;
    int ct   = (slot >> 8) & 7;
    int l    = (slot >> 11) & 1;
    int quad = lane >> 4, n = (lane & 15) + ct * 16;
    const float* Wl = W + l * D * D;
    bf16x8 v;
#pragma unroll
    for (int j = 0; j < 8; j++){
      int k = kc * 32 + quad * 8 + j;
      v[j] = (short)f2bf(Wl[k * D + n]);
    }
    *(bf16x8*)(wfrag + (size_t)slot * 8) = v;
  }
}

// ---------------- MFMA GEMM body ----------------
// h[64rows,128](bf16) = x[64rows,128]fp32 @ W ; alpha_s/d fused.
// Wave = 16-row strip; 8 col-tiles x 4 k-chunks of mfma_f32_16x16x32_bf16.
// A: lane holds A[m=lane&15][k=quad*8+j] (direct global fp32 -> cvt).
// C/D: col=lane&15, row=quad*4+reg.
__device__ __forceinline__ void gemm_mfma(int gb,
                                          const float* __restrict__ xin,
                                          const unsigned short* __restrict__ wfrag_l,
                                          const float* __restrict__ att_s,
                                          const float* __restrict__ att_d,
                                          unsigned short* __restrict__ hb,
                                          float* __restrict__ alpha_s,
                                          float* __restrict__ alpha_d){
  __shared__ __align__(16) unsigned short hstage[64 * 136]; // 272B row stride (bank-safe)
  int tid = threadIdx.x;
  int wv = tid >> 6, lane = tid & 63;
  int quad = lane >> 4, c15 = lane & 15;
  int row0 = gb * 64 + wv * 16;

  // A-fragments for the whole K (4 chunks), reused across 8 col-tiles
  int arow = min(row0 + c15, N_NODES - 1);
  const float* xr = xin + (size_t)arow * D;
  bf16x8 a[4];
#pragma unroll
  for (int kc = 0; kc < 4; kc++){
    float4 p = *(const float4*)(xr + kc * 32 + quad * 8);
    float4 q = *(const float4*)(xr + kc * 32 + quad * 8 + 4);
    bf16x8 t;
    t[0] = (short)f2bf(p.x); t[1] = (short)f2bf(p.y);
    t[2] = (short)f2bf(p.z); t[3] = (short)f2bf(p.w);
    t[4] = (short)f2bf(q.x); t[5] = (short)f2bf(q.y);
    t[6] = (short)f2bf(q.z); t[7] = (short)f2bf(q.w);
    a[kc] = t;
  }

  f32x4 acc[8];
#pragma unroll
  for (int ct = 0; ct < 8; ct++) acc[ct] = (f32x4){0.f, 0.f, 0.f, 0.f};

#pragma unroll
  for (int ct = 0; ct < 8; ct++){
#pragma unroll
    for (int kc = 0; kc < 4; kc++){
      bf16x8 b = *(const bf16x8*)(wfrag_l + ((size_t)(ct * 4 + kc) * 64 + lane) * 8);
      acc[ct] = __builtin_amdgcn_mfma_f32_16x16x32_bf16(a[kc], b, acc[ct], 0, 0, 0);
    }
  }

  // alpha epilogue from registers: lane holds rows quad*4+reg, col ct*16+c15
  float attsv[8], attdv[8];
#pragma unroll
  for (int ct = 0; ct < 8; ct++){
    attsv[ct] = att_s[ct * 16 + c15];
    attdv[ct] = att_d[ct * 16 + c15];
  }
#pragma unroll
  for (int reg = 0; reg < 4; reg++){
    float ps = 0.f, pd = 0.f;
#pragma unroll
    for (int ct = 0; ct < 8; ct++){
      ps += acc[ct][reg] * attsv[ct];
      pd += acc[ct][reg] * attdv[ct];
    }
#pragma unroll
    for (int o = 8; o; o >>= 1){                     // reduce across c15 (within quad)
      ps += __shfl_xor(ps, o, 64);
      pd += __shfl_xor(pd, o, 64);
    }
    int row = row0 + quad * 4 + reg;
    if (c15 == reg && row < N_NODES){ alpha_s[row] = ps; alpha_d[row] = pd; }
  }

  // stage h (bf16) to LDS, then coalesced write-back
#pragma unroll
  for (int ct = 0; ct < 8; ct++)
#pragma unroll
    for (int reg = 0; reg < 4; reg++)
      hstage[(wv * 16 + quad * 4 + reg) * 136 + ct * 16 + c15] = f2bf(acc[ct][reg]);
  __syncthreads();
#pragma unroll
  for (int i = 0; i < 4; i++){
    int flat = i * 256 + tid;                        // 1024 uint4 = 64 rows x 16
    int row = flat >> 4, c = flat & 15;
    int grow = gb * 64 + row;
    if (grow < N_NODES)
      *(uint4*)(hb + (size_t)grow * D + c * 8) = *(const uint4*)(hstage + row * 136 + c * 8);
  }
}

// ---------------- fused: layer-1 GEMM + bucketed CSR build ----------------
// Heterogeneous grid: GEMM blocks (MFMA-bound) co-scheduled with edge-placement
// blocks (latency-bound, 8 edges/thread for atomic ILP).
__global__ __launch_bounds__(256, 4) void k_gemm1_place(const float* __restrict__ xin,
                                                        const unsigned short* __restrict__ wfrag,
                                                        const float* __restrict__ att_s,
                                                        const float* __restrict__ att_d,
                                                        unsigned short* __restrict__ hb,
                                                        float* __restrict__ alpha_s,
                                                        float* __restrict__ alpha_d,
                                                        const int* __restrict__ ei,
                                                        const float* __restrict__ ew,
                                                        int* __restrict__ counter,
                                                        int2* __restrict__ csr, int cap){
  if (blockIdx.x < GEMM_BLOCKS){
    gemm_mfma(blockIdx.x, xin, wfrag, att_s, att_d, hb, alpha_s, alpha_d);
  } else {
    int pb = blockIdx.x - GEMM_BLOCKS;
    int e0 = pb * 2048 + threadIdx.x;
    int ss[8], dd[8], pp[8]; float wwv[8]; bool va[8];
#pragma unroll
    for (int i = 0; i < 8; i++){
      int e = e0 + i * 256;
      va[i] = e < N_EDGES;
      ss[i] = va[i] ? ei[e] : 0;
      dd[i] = va[i] ? ei[N_EDGES + e] : 0;
      wwv[i] = va[i] ? ew[e] : 0.f;
    }
#pragma unroll
    for (int i = 0; i < 8; i++) if (va[i]) pp[i] = atomicAdd(&counter[dd[i]], 1);
#pragma unroll
    for (int i = 0; i < 8; i++)
      if (va[i] && pp[i] < cap)
        csr[(size_t)dd[i] * cap + pp[i]] = make_int2(ss[i], __float_as_int(wwv[i]));
  }
}

// layer-2 GEMM alone
__global__ __launch_bounds__(256, 4) void k_gemm_alpha(const float* __restrict__ xin,
                                                       const unsigned short* __restrict__ wfrag,
                                                       const float* __restrict__ att_s,
                                                       const float* __restrict__ att_d,
                                                       unsigned short* __restrict__ hb,
                                                       float* __restrict__ alpha_s,
                                                       float* __restrict__ alpha_d){
  gemm_mfma(blockIdx.x, xin, wfrag, att_s, att_d, hb, alpha_s, alpha_d);
}

// ---------------- fused softmax + aggregation + bias + GELU (+residual/LN) ----------------
// 16 lanes per node. Inner gather loop is a FIXED 16 iterations (compile-time)
// so all 16 row-gathers are issued back-to-back (16x memory-level parallelism
// per wave instead of 1 load in flight with a runtime-trip-count loop).
// Tail lanes (j>=dg) carry p=0, s=n: they gather the node's own row (L1-hit)
// and contribute exactly 0.
template<bool LN>
__global__ __launch_bounds__(256) void k_agg(const unsigned short* __restrict__ hb,
                                             const float* __restrict__ alpha_s,
                                             const float* __restrict__ alpha_d,
                                             const int* __restrict__ counter,
                                             const int2* __restrict__ csr, int cap,
                                             const float* __restrict__ c_e, int layer,
                                             const float* __restrict__ bias,
                                             const float* __restrict__ xres,
                                             const float* __restrict__ gamma,
                                             const float* __restrict__ beta,
                                             float* __restrict__ outp){
  int lane = threadIdx.x & 63;
  int cg = lane & 15;
  int qbase = lane & 48;
  int n = blockIdx.x * 16 + (threadIdx.x >> 4);      // grid exact: N/16
  float c = c_e[layer];
  int deg = counter[n];
  int dg = min(deg, cap);
  size_t rs = (size_t)n * cap;
  float ad = alpha_d[n];
  float as_n = alpha_s[n];

  // hoisted: overlap these with the whole gather loop
  uint4 u_self = *((const uint4*)(hb + (size_t)n * D) + cg);
  const float* bptr = bias + layer * D + cg * 8;
  float4 b_lo = *(const float4*)(bptr);
  float4 b_hi = *(const float4*)(bptr + 4);
  float4 xr_lo, xr_hi, g_lo, g_hi, bt_lo, bt_hi;
  if constexpr (LN){
    const float* xr = xres + (size_t)n * D + cg * 8;
    xr_lo = *(const float4*)(xr);
    xr_hi = *(const float4*)(xr + 4);
    g_lo  = *(const float4*)(gamma + cg * 8);
    g_hi  = *(const float4*)(gamma + cg * 8 + 4);
    bt_lo = *(const float4*)(beta + cg * 8);
    bt_hi = *(const float4*)(beta + cg * 8 + 4);
  }

  float z = 0.f, wsum = 0.f;
  float acc[8];
#pragma unroll
  for (int k = 0; k < 8; k++) acc[k] = 0.f;

  for (int base = 0; base < dg; base += 16){
    int j = base + cg;
    float p = 0.f; int s = n;
    if (j < dg){
      int2 eg = csr[rs + j];
      s = eg.x;
      float w = __int_as_float(eg.y);
      wsum += w;
      p = __expf(lrelu(alpha_s[s] + ad + c * w));
    }
    z += p;
#pragma unroll
    for (int i = 0; i < 16; i++){
      float pi = __shfl(p, qbase + i, 64);
      int   si = __shfl(s, qbase + i, 64);
      uint4 u = *((const uint4*)(hb + (size_t)si * D) + cg);
      acc[0] += pi * bf_lo(u.x); acc[1] += pi * bf_hi(u.x);
      acc[2] += pi * bf_lo(u.y); acc[3] += pi * bf_hi(u.y);
      acc[4] += pi * bf_lo(u.z); acc[5] += pi * bf_hi(u.z);
      acc[6] += pi * bf_lo(u.w); acc[7] += pi * bf_hi(u.w);
    }
  }
#pragma unroll
  for (int o = 8; o; o >>= 1){
    z += __shfl_xor(z, o, 64);
    wsum += __shfl_xor(wsum, o, 64);
  }

  float lw = wsum / fmaxf((float)deg, 1.0f);
  float ps = __expf(lrelu(as_n + ad + c * lw));
  z += ps;
  acc[0] += ps * bf_lo(u_self.x); acc[1] += ps * bf_hi(u_self.x);
  acc[2] += ps * bf_lo(u_self.y); acc[3] += ps * bf_hi(u_self.y);
  acc[4] += ps * bf_lo(u_self.z); acc[5] += ps * bf_hi(u_self.z);
  acc[6] += ps * bf_lo(u_self.w); acc[7] += ps * bf_hi(u_self.w);

  float inv = 1.0f / z;
  float bv[8] = {b_lo.x, b_lo.y, b_lo.z, b_lo.w, b_hi.x, b_hi.y, b_hi.z, b_hi.w};
  float o[8];
#pragma unroll
  for (int k = 0; k < 8; k++) o[k] = gelu_exact(acc[k] * inv + bv[k]);

  if constexpr (LN){
    float xrv[8] = {xr_lo.x, xr_lo.y, xr_lo.z, xr_lo.w, xr_hi.x, xr_hi.y, xr_hi.z, xr_hi.w};
    float s1 = 0.f;
#pragma unroll
    for (int k = 0; k < 8; k++){ o[k] += xrv[k]; s1 += o[k]; }
#pragma unroll
    for (int ofs = 8; ofs; ofs >>= 1) s1 += __shfl_xor(s1, ofs, 64);
    float mu = s1 * (1.0f / D);
    float s2 = 0.f;
#pragma unroll
    for (int k = 0; k < 8; k++){ o[k] -= mu; s2 += o[k] * o[k]; }
#pragma unroll
    for (int ofs = 8; ofs; ofs >>= 1) s2 += __shfl_xor(s2, ofs, 64);
    float rinv = rsqrtf(s2 * (1.0f / D) + LN_EPS);
    float gv[8] = {g_lo.x, g_lo.y, g_lo.z, g_lo.w, g_hi.x, g_hi.y, g_hi.z, g_hi.w};
    float btv[8] = {bt_lo.x, bt_lo.y, bt_lo.z, bt_lo.w, bt_hi.x, bt_hi.y, bt_hi.z, bt_hi.w};
#pragma unroll
    for (int k = 0; k < 8; k++) o[k] = o[k] * rinv * gv[k] + btv[k];
  }

  float* orow = outp + (size_t)n * D + cg * 8;
  *(float4*)(orow)     = make_float4(o[0], o[1], o[2], o[3]);
  *(float4*)(orow + 4) = make_float4(o[4], o[5], o[6], o[7]);
}

extern "C" void kernel_launch(void* const* d_in, const int* in_sizes, int n_in,
                              void* d_out, int out_size, void* d_ws, size_t ws_size,
                              hipStream_t stream) {
  const float* x     = (const float*)d_in[0];
  const int*   ei    = (const int*)d_in[1];       // [2,E]: src then dst
  const float* ew    = (const float*)d_in[2];
  const float* W     = (const float*)d_in[3];     // [2,128,128]
  const float* att_s = (const float*)d_in[4];
  const float* att_d = (const float*)d_in[5];
  const float* lew   = (const float*)d_in[6];
  const float* ae    = (const float*)d_in[7];
  const float* bias  = (const float*)d_in[8];
  const float* gamma = (const float*)d_in[9];
  const float* beta  = (const float*)d_in[10];
  float* out = (float*)d_out;

  const int N = N_NODES;

  // bucket capacity: in-degree ~ Poisson(16); max over 100K nodes ~ 40-44.
  size_t fixed = (size_t)(3 * N + 16) * 4 + 65536;           // counter+alphas+c_e+wfrag
  size_t need64 = fixed + (size_t)N * 64 * 8 + (size_t)N * D * 2;
  int cap = (ws_size >= need64) ? 64 : 48;

  // ---- workspace carve (all offsets 16B-aligned) ----
  int*   counter  = (int*)d_ws;                 // N
  float* alpha_s  = (float*)(counter + N);      // N
  float* alpha_d  = alpha_s + N;                // N
  float* c_e      = alpha_d + N;                // 2 (+14 pad)
  unsigned short* wfrag = (unsigned short*)(c_e + 16);   // 32768 shorts (64 KB)
  int2*  csr      = (int2*)(wfrag + 32768);     // N*cap {src, weight}
  unsigned short* hb = (unsigned short*)(csr + (size_t)N * cap); // N*D bf16

  hipMemsetAsync(counter, 0, (size_t)N * sizeof(int), stream);
  k_prep<<<1, 256, 0, stream>>>(W, wfrag, lew, ae, c_e);

  // ---- layer-1 GEMM fused with CSR build ----
  k_gemm1_place<<<GEMM_BLOCKS + PLACE_BLOCKS, 256, 0, stream>>>(
      x, wfrag, att_s, att_d, hb, alpha_s, alpha_d, ei, ew, counter, csr, cap);

  k_agg<false><<<N / 16, 256, 0, stream>>>(hb, alpha_s, alpha_d, counter, csr, cap,
                                           c_e, 0, bias, nullptr, nullptr, nullptr, out);

  // ---- layer 2 (+ fused residual & LayerNorm) ----
  k_gemm_alpha<<<GEMM_BLOCKS, 256, 0, stream>>>(out, wfrag + 16384, att_s + D, att_d + D,
                                                hb, alpha_s, alpha_d);
  k_agg<true><<<N / 16, 256, 0, stream>>>(hb, alpha_s, alpha_d, counter, csr, cap,
                                          c_e, 1, bias, x, gamma, beta, out);
}

// Round 2
// 432.261 us; speedup vs baseline: 1.1071x; 1.1071x over previous
//
#include <hip/hip_runtime.h>
#include <hip/hip_bf16.h>
#include <math.h>

#define N_NODES 100000
#define N_EDGES 1600000
#define D 128
#define NEG 0.2f
#define LN_EPS 1e-5f

#define GEMM_BLOCKS ((N_NODES + 63) / 64)       // 1563 (64 rows/block)
#define PLACE_BLOCKS ((N_EDGES + 1023) / 1024)  // 1563 (1024 edges/block, 4/thread)

typedef __attribute__((ext_vector_type(8))) short bf16x8;
typedef __attribute__((ext_vector_type(4))) float f32x4;

__device__ __forceinline__ float lrelu(float v){ return fmaxf(v, NEG * v); }
__device__ __forceinline__ float gelu_exact(float v){ return 0.5f * v * (1.0f + erff(v * 0.7071067811865476f)); }
__device__ __forceinline__ float wave_sum(float v){
#pragma unroll
  for (int o = 32; o; o >>= 1) v += __shfl_xor(v, o, 64);
  return v;
}
__device__ __forceinline__ unsigned short f2bf(float f){
  __hip_bfloat16 h = __float2bfloat16(f);            // RNE
  return *(unsigned short*)&h;
}
// bf16 pair unpack: low 16 bits = even col, high = odd col
__device__ __forceinline__ float bf_lo(unsigned u){ return __uint_as_float(u << 16); }
__device__ __forceinline__ float bf_hi(unsigned u){ return __uint_as_float(u & 0xFFFF0000u); }

// ---------------- prep: W -> B-fragment bf16 layout + c_e ----------------
// Wfrag slot = ((l*8+ct)*4+kc)*64+lane, 8 bf16 each:
//   Wfrag[slot][j] = bf16( W[l][ kc*32 + (lane>>4)*8 + j ][ ct*16 + (lane&15) ] )
__global__ __launch_bounds__(256) void k_prep(const float* __restrict__ W,
                                              unsigned short* __restrict__ wfrag,
                                              const float* __restrict__ lew,
                                              const float* __restrict__ ae,
                                              float* __restrict__ c_e){
  if (threadIdx.x < 128){
    int l = threadIdx.x >> 6;
    int lane = threadIdx.x & 63;
    const float* a = lew + l * D;
    const float* b = ae + l * D;
    float v = a[lane] * b[lane] + a[64 + lane] * b[64 + lane];
    v = wave_sum(v);
    if (lane == 0) c_e[l] = v;
  }
#pragma unroll
  for (int it = 0; it < 16; it++){
    int slot = it * 256 + threadIdx.x;               // 4096 slots
    int lane = slot & 63;
    int kc   = (slot >> 6) & 3;
    int ct   = (slot >> 8) & 7;
    int l    = (slot >> 11) & 1;
    int quad = lane >> 4, n = (lane & 15) + ct * 16;
    const float* Wl = W + l * D * D;
    bf16x8 v;
#pragma unroll
    for (int j = 0; j < 8; j++){
      int k = kc * 32 + quad * 8 + j;
      v[j] = (short)f2bf(Wl[k * D + n]);
    }
    *(bf16x8*)(wfrag + (size_t)slot * 8) = v;
  }
}

// ---------------- MFMA GEMM body ----------------
// h[64rows,128](bf16) = A[64rows,128] @ W ; alpha_s/d fused.
// A input either fp32 (layer 1: x) or bf16 (layer 2: gelu-out stored bf16 —
// identical numerics to fp32+f2bf since the cvt point is just moved).
// Wave = 16-row strip; 8 col-tiles x 4 k-chunks of mfma_f32_16x16x32_bf16.
// A: lane holds A[m=lane&15][k=quad*8+j].
// C/D: col=lane&15, row=quad*4+reg.
template<bool ABF>
__device__ __forceinline__ void gemm_mfma(int gb,
                                          const void* __restrict__ xin_,
                                          const unsigned short* __restrict__ wfrag_l,
                                          const float* __restrict__ att_s,
                                          const float* __restrict__ att_d,
                                          unsigned short* __restrict__ hb,
                                          float* __restrict__ alpha_s,
                                          float* __restrict__ alpha_d){
  __shared__ __align__(16) unsigned short hstage[64 * 136]; // 272B row stride (bank-safe)
  int tid = threadIdx.x;
  int wv = tid >> 6, lane = tid & 63;
  int quad = lane >> 4, c15 = lane & 15;
  int row0 = gb * 64 + wv * 16;

  // A-fragments for the whole K (4 chunks), reused across 8 col-tiles
  int arow = min(row0 + c15, N_NODES - 1);
  bf16x8 a[4];
  if constexpr (ABF){
    const unsigned short* xr = (const unsigned short*)xin_ + (size_t)arow * D;
#pragma unroll
    for (int kc = 0; kc < 4; kc++)
      a[kc] = *(const bf16x8*)(xr + kc * 32 + quad * 8);
  } else {
    const float* xr = (const float*)xin_ + (size_t)arow * D;
#pragma unroll
    for (int kc = 0; kc < 4; kc++){
      float4 p = *(const float4*)(xr + kc * 32 + quad * 8);
      float4 q = *(const float4*)(xr + kc * 32 + quad * 8 + 4);
      bf16x8 t;
      t[0] = (short)f2bf(p.x); t[1] = (short)f2bf(p.y);
      t[2] = (short)f2bf(p.z); t[3] = (short)f2bf(p.w);
      t[4] = (short)f2bf(q.x); t[5] = (short)f2bf(q.y);
      t[6] = (short)f2bf(q.z); t[7] = (short)f2bf(q.w);
      a[kc] = t;
    }
  }

  f32x4 acc[8];
#pragma unroll
  for (int ct = 0; ct < 8; ct++) acc[ct] = (f32x4){0.f, 0.f, 0.f, 0.f};

#pragma unroll
  for (int ct = 0; ct < 8; ct++){
#pragma unroll
    for (int kc = 0; kc < 4; kc++){
      bf16x8 b = *(const bf16x8*)(wfrag_l + ((size_t)(ct * 4 + kc) * 64 + lane) * 8);
      acc[ct] = __builtin_amdgcn_mfma_f32_16x16x32_bf16(a[kc], b, acc[ct], 0, 0, 0);
    }
  }

  // alpha epilogue from registers: lane holds rows quad*4+reg, col ct*16+c15
  float attsv[8], attdv[8];
#pragma unroll
  for (int ct = 0; ct < 8; ct++){
    attsv[ct] = att_s[ct * 16 + c15];
    attdv[ct] = att_d[ct * 16 + c15];
  }
#pragma unroll
  for (int reg = 0; reg < 4; reg++){
    float ps = 0.f, pd = 0.f;
#pragma unroll
    for (int ct = 0; ct < 8; ct++){
      ps += acc[ct][reg] * attsv[ct];
      pd += acc[ct][reg] * attdv[ct];
    }
#pragma unroll
    for (int o = 8; o; o >>= 1){                     // reduce across c15 (within quad)
      ps += __shfl_xor(ps, o, 64);
      pd += __shfl_xor(pd, o, 64);
    }
    int row = row0 + quad * 4 + reg;
    if (c15 == reg && row < N_NODES){ alpha_s[row] = ps; alpha_d[row] = pd; }
  }

  // stage h (bf16) to LDS, then coalesced write-back
#pragma unroll
  for (int ct = 0; ct < 8; ct++)
#pragma unroll
    for (int reg = 0; reg < 4; reg++)
      hstage[(wv * 16 + quad * 4 + reg) * 136 + ct * 16 + c15] = f2bf(acc[ct][reg]);
  __syncthreads();
#pragma unroll
  for (int i = 0; i < 4; i++){
    int flat = i * 256 + tid;                        // 1024 uint4 = 64 rows x 16
    int row = flat >> 4, c = flat & 15;
    int grow = gb * 64 + row;
    if (grow < N_NODES)
      *(uint4*)(hb + (size_t)grow * D + c * 8) = *(const uint4*)(hstage + row * 136 + c * 8);
  }
}

// ---------------- fused: layer-1 GEMM + bucketed CSR build ----------------
// Heterogeneous grid. Placement blocks come FIRST so their long atomic
// latency chains start immediately; GEMM blocks (MFMA-bound) backfill.
// Placement: 4 edges/thread, 1563 blocks (measured best: occupancy/wave-count
// matters more than per-thread ILP for the atomic chain).
__global__ __launch_bounds__(256, 4) void k_gemm1_place(const float* __restrict__ xin,
                                                        const unsigned short* __restrict__ wfrag,
                                                        const float* __restrict__ att_s,
                                                        const float* __restrict__ att_d,
                                                        unsigned short* __restrict__ hb,
                                                        float* __restrict__ alpha_s,
                                                        float* __restrict__ alpha_d,
                                                        const int* __restrict__ ei,
                                                        const float* __restrict__ ew,
                                                        int* __restrict__ counter,
                                                        int2* __restrict__ csr, int cap){
  if (blockIdx.x >= PLACE_BLOCKS){
    gemm_mfma<false>(blockIdx.x - PLACE_BLOCKS, xin, wfrag, att_s, att_d, hb, alpha_s, alpha_d);
  } else {
    int pb = blockIdx.x;
    int e0 = pb * 1024 + threadIdx.x;
    int ss[4], dd[4], pp[4]; float wwv[4]; bool va[4];
#pragma unroll
    for (int i = 0; i < 4; i++){
      int e = e0 + i * 256;
      va[i] = e < N_EDGES;
      ss[i] = va[i] ? ei[e] : 0;
      dd[i] = va[i] ? ei[N_EDGES + e] : 0;
      wwv[i] = va[i] ? ew[e] : 0.f;
    }
#pragma unroll
    for (int i = 0; i < 4; i++) if (va[i]) pp[i] = atomicAdd(&counter[dd[i]], 1);
#pragma unroll
    for (int i = 0; i < 4; i++)
      if (va[i] && pp[i] < cap)
        csr[(size_t)dd[i] * cap + pp[i]] = make_int2(ss[i], __float_as_int(wwv[i]));
  }
}

// layer-2 GEMM alone (A input is bf16 from layer-1 k_agg)
__global__ __launch_bounds__(256, 4) void k_gemm_alpha(const unsigned short* __restrict__ xin,
                                                       const unsigned short* __restrict__ wfrag,
                                                       const float* __restrict__ att_s,
                                                       const float* __restrict__ att_d,
                                                       unsigned short* __restrict__ hb,
                                                       float* __restrict__ alpha_s,
                                                       float* __restrict__ alpha_d){
  gemm_mfma<true>(blockIdx.x, xin, wfrag, att_s, att_d, hb, alpha_s, alpha_d);
}

// ---------------- fused softmax + aggregation + bias + GELU (+residual/LN) ----------------
// 16 lanes per node. Inner gather loop is a FIXED 16 iterations (compile-time)
// so all 16 row-gathers are issued back-to-back. Tail lanes (j>=dg) carry
// p=0, s=n: they re-gather the node's own (cache-hot) row, contributing 0.
// LN=false (layer 1): output written as bf16 (it only feeds the layer-2 GEMM,
// which would f2bf it anyway — identical numerics, half the traffic).
// LN=true (layer 2): residual + LayerNorm, fp32 output.
template<bool LN>
__global__ __launch_bounds__(256) void k_agg(const unsigned short* __restrict__ hb,
                                             const float* __restrict__ alpha_s,
                                             const float* __restrict__ alpha_d,
                                             const int* __restrict__ counter,
                                             const int2* __restrict__ csr, int cap,
                                             const float* __restrict__ c_e, int layer,
                                             const float* __restrict__ bias,
                                             const float* __restrict__ xres,
                                             const float* __restrict__ gamma,
                                             const float* __restrict__ beta,
                                             float* __restrict__ outp,
                                             unsigned short* __restrict__ outp_bf){
  int lane = threadIdx.x & 63;
  int cg = lane & 15;
  int qbase = lane & 48;
  int n = blockIdx.x * 16 + (threadIdx.x >> 4);      // grid exact: N/16
  float c = c_e[layer];
  int deg = counter[n];
  int dg = min(deg, cap);
  size_t rs = (size_t)n * cap;
  float ad = alpha_d[n];
  float as_n = alpha_s[n];

  // hoisted: overlap these with the whole gather loop
  uint4 u_self = *((const uint4*)(hb + (size_t)n * D) + cg);
  const float* bptr = bias + layer * D + cg * 8;
  float4 b_lo = *(const float4*)(bptr);
  float4 b_hi = *(const float4*)(bptr + 4);
  float4 xr_lo, xr_hi, g_lo, g_hi, bt_lo, bt_hi;
  if constexpr (LN){
    const float* xr = xres + (size_t)n * D + cg * 8;
    xr_lo = *(const float4*)(xr);
    xr_hi = *(const float4*)(xr + 4);
    g_lo  = *(const float4*)(gamma + cg * 8);
    g_hi  = *(const float4*)(gamma + cg * 8 + 4);
    bt_lo = *(const float4*)(beta + cg * 8);
    bt_hi = *(const float4*)(beta + cg * 8 + 4);
  }

  float z = 0.f, wsum = 0.f;
  float acc[8];
#pragma unroll
  for (int k = 0; k < 8; k++) acc[k] = 0.f;

  for (int base = 0; base < dg; base += 16){
    int j = base + cg;
    float p = 0.f; int s = n;
    if (j < dg){
      int2 eg = csr[rs + j];
      s = eg.x;
      float w = __int_as_float(eg.y);
      wsum += w;
      p = __expf(lrelu(alpha_s[s] + ad + c * w));
    }
    z += p;
#pragma unroll
    for (int i = 0; i < 16; i++){
      float pi = __shfl(p, qbase + i, 64);
      int   si = __shfl(s, qbase + i, 64);
      uint4 u = *((const uint4*)(hb + (size_t)si * D) + cg);
      acc[0] += pi * bf_lo(u.x); acc[1] += pi * bf_hi(u.x);
      acc[2] += pi * bf_lo(u.y); acc[3] += pi * bf_hi(u.y);
      acc[4] += pi * bf_lo(u.z); acc[5] += pi * bf_hi(u.z);
      acc[6] += pi * bf_lo(u.w); acc[7] += pi * bf_hi(u.w);
    }
  }
#pragma unroll
  for (int o = 8; o; o >>= 1){
    z += __shfl_xor(z, o, 64);
    wsum += __shfl_xor(wsum, o, 64);
  }

  float lw = wsum / fmaxf((float)deg, 1.0f);
  float ps = __expf(lrelu(as_n + ad + c * lw));
  z += ps;
  acc[0] += ps * bf_lo(u_self.x); acc[1] += ps * bf_hi(u_self.x);
  acc[2] += ps * bf_lo(u_self.y); acc[3] += ps * bf_hi(u_self.y);
  acc[4] += ps * bf_lo(u_self.z); acc[5] += ps * bf_hi(u_self.z);
  acc[6] += ps * bf_lo(u_self.w); acc[7] += ps * bf_hi(u_self.w);

  float inv = 1.0f / z;
  float bv[8] = {b_lo.x, b_lo.y, b_lo.z, b_lo.w, b_hi.x, b_hi.y, b_hi.z, b_hi.w};
  float o[8];
#pragma unroll
  for (int k = 0; k < 8; k++) o[k] = gelu_exact(acc[k] * inv + bv[k]);

  if constexpr (LN){
    float xrv[8] = {xr_lo.x, xr_lo.y, xr_lo.z, xr_lo.w, xr_hi.x, xr_hi.y, xr_hi.z, xr_hi.w};
    float s1 = 0.f;
#pragma unroll
    for (int k = 0; k < 8; k++){ o[k] += xrv[k]; s1 += o[k]; }
#pragma unroll
    for (int ofs = 8; ofs; ofs >>= 1) s1 += __shfl_xor(s1, ofs, 64);
    float mu = s1 * (1.0f / D);
    float s2 = 0.f;
#pragma unroll
    for (int k = 0; k < 8; k++){ o[k] -= mu; s2 += o[k] * o[k]; }
#pragma unroll
    for (int ofs = 8; ofs; ofs >>= 1) s2 += __shfl_xor(s2, ofs, 64);
    float rinv = rsqrtf(s2 * (1.0f / D) + LN_EPS);
    float gv[8] = {g_lo.x, g_lo.y, g_lo.z, g_lo.w, g_hi.x, g_hi.y, g_hi.z, g_hi.w};
    float btv[8] = {bt_lo.x, bt_lo.y, bt_lo.z, bt_lo.w, bt_hi.x, bt_hi.y, bt_hi.z, bt_hi.w};
#pragma unroll
    for (int k = 0; k < 8; k++) o[k] = o[k] * rinv * gv[k] + btv[k];
    float* orow = outp + (size_t)n * D + cg * 8;
    *(float4*)(orow)     = make_float4(o[0], o[1], o[2], o[3]);
    *(float4*)(orow + 4) = make_float4(o[4], o[5], o[6], o[7]);
  } else {
    // bf16 output -> feeds layer-2 GEMM A directly (same RNE rounding point)
    unsigned short ob[8];
#pragma unroll
    for (int k = 0; k < 8; k++) ob[k] = f2bf(o[k]);
    *(uint4*)(outp_bf + (size_t)n * D + cg * 8) = *(const uint4*)ob;
  }
}

extern "C" void kernel_launch(void* const* d_in, const int* in_sizes, int n_in,
                              void* d_out, int out_size, void* d_ws, size_t ws_size,
                              hipStream_t stream) {
  const float* x     = (const float*)d_in[0];
  const int*   ei    = (const int*)d_in[1];       // [2,E]: src then dst
  const float* ew    = (const float*)d_in[2];
  const float* W     = (const float*)d_in[3];     // [2,128,128]
  const float* att_s = (const float*)d_in[4];
  const float* att_d = (const float*)d_in[5];
  const float* lew   = (const float*)d_in[6];
  const float* ae    = (const float*)d_in[7];
  const float* bias  = (const float*)d_in[8];
  const float* gamma = (const float*)d_in[9];
  const float* beta  = (const float*)d_in[10];
  float* out = (float*)d_out;

  const int N = N_NODES;

  // bucket capacity: in-degree ~ Poisson(16); max over 100K nodes ~ 40-44.
  size_t fixed = (size_t)(3 * N + 16) * 4 + 65536;           // counter+alphas+c_e+wfrag
  size_t need64 = fixed + (size_t)N * 64 * 8 + (size_t)N * D * 2;
  int cap = (ws_size >= need64) ? 64 : 48;

  // ---- workspace carve (all offsets 16B-aligned) ----
  int*   counter  = (int*)d_ws;                 // N
  float* alpha_s  = (float*)(counter + N);      // N
  float* alpha_d  = alpha_s + N;                // N
  float* c_e      = alpha_d + N;                // 2 (+14 pad)
  unsigned short* wfrag = (unsigned short*)(c_e + 16);   // 32768 shorts (64 KB)
  int2*  csr      = (int2*)(wfrag + 32768);     // N*cap {src, weight}
  unsigned short* hb = (unsigned short*)(csr + (size_t)N * cap); // N*D bf16

  // layer-1 bf16 output lives in the d_out buffer (N*D bf16 fits in N*D fp32);
  // it is fully consumed by k_gemm_alpha before k_agg<true> overwrites d_out.
  unsigned short* h1b = (unsigned short*)d_out;

  hipMemsetAsync(counter, 0, (size_t)N * sizeof(int), stream);
  k_prep<<<1, 256, 0, stream>>>(W, wfrag, lew, ae, c_e);

  // ---- layer-1 GEMM fused with CSR build ----
  k_gemm1_place<<<GEMM_BLOCKS + PLACE_BLOCKS, 256, 0, stream>>>(
      x, wfrag, att_s, att_d, hb, alpha_s, alpha_d, ei, ew, counter, csr, cap);

  k_agg<false><<<N / 16, 256, 0, stream>>>(hb, alpha_s, alpha_d, counter, csr, cap,
                                           c_e, 0, bias, nullptr, nullptr, nullptr,
                                           nullptr, h1b);

  // ---- layer 2 (+ fused residual & LayerNorm) ----
  k_gemm_alpha<<<GEMM_BLOCKS, 256, 0, stream>>>(h1b, wfrag + 16384, att_s + D, att_d + D,
                                                hb, alpha_s, alpha_d);
  k_agg<true><<<N / 16, 256, 0, stream>>>(hb, alpha_s, alpha_d, counter, csr, cap,
                                          c_e, 1, bias, x, gamma, beta, out, nullptr);
}